// Round 2
// baseline (1097.994 us; speedup 1.0000x reference)
//
#include <hip/hip_runtime.h>
#include <float.h>

// Problem constants (from reference file)
constexpr int C    = 512;          // DIM_CODES
constexpr int K    = 512;          // DICT_SIZE
constexpr int E    = 16;           // EMBED_DIM
constexpr int B    = 512;          // BATCH
constexpr int ROWS = 128;          // batches per block
constexpr int MUS  = C * E;        // 8192, mu row stride

// Block = one code-dim c x 128 batch rows; 4 waves. Each wave owns the full
// 512x16 dict slice in registers (8 codes/lane, 128 VGPRs) and processes
// 32 rows. Rows are handled 4-at-a-time so the cross-lane argmin butterflies
// (ds_bpermute, LDS-class latency) overlap via ILP instead of serializing.
// Per-row state in the butterfly: u64 (dist_bits<<32)|k  -> one v_cmp_lt_u64
// gives exact min-dist + first-index tiebreak; sec (runner-up) is folded into
// the same pass: sec' = min(secA, secB, max(bestA, bestB)).
__launch_bounds__(256, 2)
__global__ void vq_kernel(const float* __restrict__ mu,
                          const float* __restrict__ dict,
                          float* __restrict__ z,
                          float* __restrict__ zq,
                          float* __restrict__ oh)
{
    const int c    = blockIdx.x;
    const int b0   = blockIdx.y * ROWS;
    const int tid  = threadIdx.x;
    const int lane = tid & 63;
    const int wave = tid >> 6;

    __shared__ float mu_s[ROWS][E];    // 8 KB

    const float* __restrict__ dbase = dict + (size_t)c * K * E;

    // ---- dict slice -> registers, plus per-code squared norms
    float4 dv[8][4];
    float  nrm[8];
#pragma unroll
    for (int i = 0; i < 8; ++i) {
        const int k = lane + 64 * i;
        const float4* p = reinterpret_cast<const float4*>(dbase + k * E);
        dv[i][0] = p[0]; dv[i][1] = p[1]; dv[i][2] = p[2]; dv[i][3] = p[3];
        float s = dv[i][0].x * dv[i][0].x;
        s = fmaf(dv[i][0].y, dv[i][0].y, s);
        s = fmaf(dv[i][0].z, dv[i][0].z, s);
        s = fmaf(dv[i][0].w, dv[i][0].w, s);
#pragma unroll
        for (int t = 1; t < 4; ++t) {
            s = fmaf(dv[i][t].x, dv[i][t].x, s);
            s = fmaf(dv[i][t].y, dv[i][t].y, s);
            s = fmaf(dv[i][t].z, dv[i][t].z, s);
            s = fmaf(dv[i][t].w, dv[i][t].w, s);
        }
        nrm[i] = s;
    }

    // ---- stage the 128x16 mu sub-block into LDS
    {
        const int r = tid >> 2, q = tid & 3;
#pragma unroll
        for (int rep = 0; rep < 2; ++rep) {
            const int row = r + rep * 64;
            const float4* p = reinterpret_cast<const float4*>(
                mu + (size_t)(b0 + row) * MUS + c * E);
            reinterpret_cast<float4*>(&mu_s[row][0])[q] = p[q];
        }
    }
    __syncthreads();

    // wave w handles rows {w + 4t : t=0..31}; 4 rows per iteration.
    for (int j = 0; j < ROWS / 16; ++j) {
        unsigned long long pk[4];
        float              sec[4];

        // ---------- phase 1: per-lane distances + per-lane (best, sec)
#pragma unroll
        for (int r = 0; r < 4; ++r) {
            const int bl = wave + 16 * j + 4 * r;

            float4 m[4];
#pragma unroll
            for (int t = 0; t < 4; ++t)
                m[t] = reinterpret_cast<const float4*>(&mu_s[bl][0])[t];

            float nmu = m[0].x * m[0].x;
            nmu = fmaf(m[0].y, m[0].y, nmu);
            nmu = fmaf(m[0].z, m[0].z, nmu);
            nmu = fmaf(m[0].w, m[0].w, nmu);
#pragma unroll
            for (int t = 1; t < 4; ++t) {
                nmu = fmaf(m[t].x, m[t].x, nmu);
                nmu = fmaf(m[t].y, m[t].y, nmu);
                nmu = fmaf(m[t].z, m[t].z, nmu);
                nmu = fmaf(m[t].w, m[t].w, nmu);
            }

            float best_d = FLT_MAX;
            int   best_k = K;
            float sc     = FLT_MAX;
#pragma unroll
            for (int i = 0; i < 8; ++i) {
                float acc = dv[i][0].x * m[0].x;
                acc = fmaf(dv[i][0].y, m[0].y, acc);
                acc = fmaf(dv[i][0].z, m[0].z, acc);
                acc = fmaf(dv[i][0].w, m[0].w, acc);
#pragma unroll
                for (int t = 1; t < 4; ++t) {
                    acc = fmaf(dv[i][t].x, m[t].x, acc);
                    acc = fmaf(dv[i][t].y, m[t].y, acc);
                    acc = fmaf(dv[i][t].z, m[t].z, acc);
                    acc = fmaf(dv[i][t].w, m[t].w, acc);
                }
                const float dist = fmaf(-2.0f, acc, nmu + nrm[i]);
                // runner-up candidate = loser of (best_d, dist)
                sc = fminf(sc, fmaxf(best_d, dist));
                if (dist < best_d) { best_d = dist; best_k = lane + 64 * i; }
            }
            pk[r]  = ((unsigned long long)__float_as_uint(best_d) << 32)
                   | (unsigned)best_k;
            sec[r] = sc;
        }

        // ---------- phase 2: 4 interleaved butterfly reductions
#pragma unroll
        for (int off = 32; off; off >>= 1) {
            unsigned long long opk[4];
            float              osec[4];
#pragma unroll
            for (int r = 0; r < 4; ++r) {
                opk[r]  = __shfl_down(pk[r], off);
                osec[r] = __shfl_down(sec[r], off);
            }
#pragma unroll
            for (int r = 0; r < 4; ++r) {
                const float a  = __uint_as_float((unsigned)(pk[r]  >> 32));
                const float b2 = __uint_as_float((unsigned)(opk[r] >> 32));
                sec[r] = fminf(fminf(sec[r], osec[r]), fmaxf(a, b2));
                if (opk[r] < pk[r]) pk[r] = opk[r];
            }
        }

        // ---------- phase 3: broadcast result (scalar) + rare fp64 re-check
        int bk0 = 0, bk1 = 0, bk2 = 0, bk3 = 0;
#pragma unroll
        for (int r = 0; r < 4; ++r) {
            const int klo = __builtin_amdgcn_readfirstlane((int)(unsigned)pk[r]);
            const int dhi = __builtin_amdgcn_readfirstlane((int)(pk[r] >> 32));
            const int shi = __builtin_amdgcn_readfirstlane(__float_as_int(sec[r]));
            int  bkr = klo;
            const float bd = __int_as_float(dhi);
            const float sc = __int_as_float(shi);

            if (sc - bd < 1e-3f) {   // wave-uniform, rare: exact fp64 path
                const int bl = wave + 16 * j + 4 * r;
                float4 m[4];
#pragma unroll
                for (int t = 0; t < 4; ++t)
                    m[t] = reinterpret_cast<const float4*>(&mu_s[bl][0])[t];
                double nmuD = 0.0;
#pragma unroll
                for (int t = 0; t < 4; ++t) {
                    nmuD += (double)m[t].x * m[t].x + (double)m[t].y * m[t].y
                          + (double)m[t].z * m[t].z + (double)m[t].w * m[t].w;
                }
                double bdd = DBL_MAX;
                int    bkk = K;
#pragma unroll
                for (int i = 0; i < 8; ++i) {
                    double nd = 0.0, dt = 0.0;
#pragma unroll
                    for (int t = 0; t < 4; ++t) {
                        nd += (double)dv[i][t].x * dv[i][t].x
                            + (double)dv[i][t].y * dv[i][t].y
                            + (double)dv[i][t].z * dv[i][t].z
                            + (double)dv[i][t].w * dv[i][t].w;
                        dt += (double)dv[i][t].x * m[t].x
                            + (double)dv[i][t].y * m[t].y
                            + (double)dv[i][t].z * m[t].z
                            + (double)dv[i][t].w * m[t].w;
                    }
                    const double dist = nmuD + nd - 2.0 * dt;
                    const int k = lane + 64 * i;
                    if (dist < bdd) { bdd = dist; bkk = k; }
                }
#pragma unroll
                for (int off = 32; off; off >>= 1) {
                    const double od = __shfl_down(bdd, off);
                    const int    ok = __shfl_down(bkk, off);
                    if (od < bdd || (od == bdd && ok < bkk)) { bdd = od; bkk = ok; }
                }
                bkr = __builtin_amdgcn_readfirstlane(bkk);
            }

            if (r == 0) bk0 = bkr; else if (r == 1) bk1 = bkr;
            else if (r == 2) bk2 = bkr; else bk3 = bkr;

            // ---------- one_hot row: two coalesced float4 stores per lane
            const int bl = wave + 16 * j + 4 * r;
            float* ohp = oh + ((size_t)(b0 + bl) * C + c) * K;
#pragma unroll
            for (int h = 0; h < 2; ++h) {
                const int kb = h * 256 + lane * 4;
                float4 v;
                v.x = (kb + 0 == bkr) ? 1.0f : 0.0f;
                v.y = (kb + 1 == bkr) ? 1.0f : 0.0f;
                v.z = (kb + 2 == bkr) ? 1.0f : 0.0f;
                v.w = (kb + 3 == bkr) ? 1.0f : 0.0f;
                *reinterpret_cast<float4*>(ohp + kb) = v;
            }
        }

        // ---------- phase 4: z / zq for all 4 rows with one full wave
        {
            const int r = lane >> 4;        // sub-row 0..3
            const int e = lane & 15;        // embed dim
            int bkr = bk0;
            bkr = (r == 1) ? bk1 : bkr;
            bkr = (r == 2) ? bk2 : bkr;
            bkr = (r == 3) ? bk3 : bkr;
            const int bl = wave + 16 * j + 4 * r;
            const float dq = dbase[bkr * E + e];   // L2-hot
            const float mm = mu_s[bl][e];
            const size_t o = (size_t)(b0 + bl) * MUS + (size_t)c * E + e;
            zq[o] = dq;
            z[o]  = mm + (dq - mm);                // fp32 op-for-op like ref
        }
    }
}

extern "C" void kernel_launch(void* const* d_in, const int* in_sizes, int n_in,
                              void* d_out, int out_size, void* d_ws, size_t ws_size,
                              hipStream_t stream)
{
    const float* mu   = (const float*)d_in[0];
    const float* dict = (const float*)d_in[1];

    float* z  = (float*)d_out;                 // (B, C*E)
    float* zq = z  + (size_t)B * C * E;        // (B, C*E)
    float* oh = zq + (size_t)B * C * E;        // (B, C, K)

    dim3 grid(C, B / ROWS);
    vq_kernel<<<grid, 256, 0, stream>>>(mu, dict, z, zq, oh);
}

// Round 3
// 781.940 us; speedup vs baseline: 1.4042x; 1.4042x over previous
//
#include <hip/hip_runtime.h>
#include <float.h>

// Problem constants (from reference file)
constexpr int C    = 512;          // DIM_CODES
constexpr int K    = 512;          // DICT_SIZE
constexpr int E    = 16;           // EMBED_DIM
constexpr int B    = 512;          // BATCH
constexpr int ROWS = 128;          // batches per block
constexpr int MUS  = C * E;        // 8192, mu row stride

// fp32 chained-FMA dot, op-for-op identical to the verified round-2 kernel:
// fmaf(x,x,0) == x*x exactly, then y,z,w FMAs in order.
__device__ __forceinline__ float fdot4(const float4 a, const float4 b, float acc) {
    acc = fmaf(a.x, b.x, acc);
    acc = fmaf(a.y, b.y, acc);
    acc = fmaf(a.z, b.z, acc);
    acc = fmaf(a.w, b.w, acc);
    return acc;
}
// fp64 accumulation, same expression shape as round 2 (4 products summed,
// then added to acc).
__device__ __forceinline__ double ddot4(const float4 a, const float4 b, double acc) {
    return acc + ((double)a.x * b.x + (double)a.y * b.y
                + (double)a.z * b.z + (double)a.w * b.w);
}
__device__ __forceinline__ double dnrm4(const float4 a, double acc) {
    return acc + ((double)a.x * a.x + (double)a.y * a.y
                + (double)a.z * a.z + (double)a.w * a.w);
}

// Block = one code-dim c x 128 batch rows; 4 waves. Each wave owns the full
// 512x16 dict slice in NAMED registers (8 codes/lane = 32 float4 + 8 norms;
// named scalars so SROA cannot demote them to a scratch array). Rows go
// 4-at-a-time so the cross-lane argmin butterflies overlap via ILP.
//
// __launch_bounds__(256, 1): round-2's (256,2) capped the allocator at 128
// VGPRs (unified 512-reg file / 2 waves, no AGPRs) and spilled the 128-reg
// dict slice to scratch -> 1.74 GB HBM fetch, 718 us. (256,1) lifts the cap;
// ~190 VGPRs still yields 2 waves/EU.
__launch_bounds__(256, 1)
__global__ void vq_kernel(const float* __restrict__ mu,
                          const float* __restrict__ dict,
                          float* __restrict__ z,
                          float* __restrict__ zq,
                          float* __restrict__ oh)
{
    const int c    = blockIdx.x;
    const int b0   = blockIdx.y * ROWS;
    const int tid  = threadIdx.x;
    const int lane = tid & 63;
    const int wave = tid >> 6;

    __shared__ float mu_s[ROWS][E];    // 8 KB

    const float* __restrict__ dbase = dict + (size_t)c * K * E;

#define FOR8(X) X(0) X(1) X(2) X(3) X(4) X(5) X(6) X(7)

    // ---- dict slice -> named registers + per-code squared norms
#define DECL_D(i) float4 d##i##_0, d##i##_1, d##i##_2, d##i##_3; float n##i;
    FOR8(DECL_D)
#undef DECL_D

#define LOAD_D(i) { \
    const float4* p = reinterpret_cast<const float4*>( \
        dbase + (size_t)(lane + 64 * i) * E); \
    d##i##_0 = p[0]; d##i##_1 = p[1]; d##i##_2 = p[2]; d##i##_3 = p[3]; \
    float s = fdot4(d##i##_0, d##i##_0, 0.0f); \
    s = fdot4(d##i##_1, d##i##_1, s); \
    s = fdot4(d##i##_2, d##i##_2, s); \
    s = fdot4(d##i##_3, d##i##_3, s); \
    n##i = s; }
    FOR8(LOAD_D)
#undef LOAD_D

    // ---- stage the 128x16 mu sub-block into LDS
    {
        const int r = tid >> 2, q = tid & 3;
#pragma unroll
        for (int rep = 0; rep < 2; ++rep) {
            const int row = r + rep * 64;
            const float4* p = reinterpret_cast<const float4*>(
                mu + (size_t)(b0 + row) * MUS + c * E);
            reinterpret_cast<float4*>(&mu_s[row][0])[q] = p[q];
        }
    }
    __syncthreads();

    // wave w handles rows {w + 4t}; 4 rows per j-iteration.
    // unroll 1: keeps 4 (not 32) copies of the cold fp64 path -> I-cache.
#pragma unroll 1
    for (int j = 0; j < ROWS / 16; ++j) {
        unsigned long long pk0, pk1, pk2, pk3;
        float sec0, sec1, sec2, sec3;

        // ---------- phase 1: per-lane distances + per-lane (best, sec)
#define DIST1(i) { \
    float acc = fdot4(d##i##_0, m0, 0.0f); \
    acc = fdot4(d##i##_1, m1, acc); \
    acc = fdot4(d##i##_2, m2, acc); \
    acc = fdot4(d##i##_3, m3, acc); \
    const float dist = fmaf(-2.0f, acc, nmu + n##i); \
    sc = fminf(sc, fmaxf(best_d, dist)); \
    if (dist < best_d) { best_d = dist; best_k = lane + 64 * i; } }

#define PHASE1(r) { \
    const int bl = wave + 16 * j + 4 * r; \
    const float4* mp = reinterpret_cast<const float4*>(&mu_s[bl][0]); \
    const float4 m0 = mp[0], m1 = mp[1], m2 = mp[2], m3 = mp[3]; \
    float nmu = fdot4(m0, m0, 0.0f); \
    nmu = fdot4(m1, m1, nmu); \
    nmu = fdot4(m2, m2, nmu); \
    nmu = fdot4(m3, m3, nmu); \
    float best_d = FLT_MAX; \
    int   best_k = K; \
    float sc     = FLT_MAX; \
    FOR8(DIST1) \
    pk##r = ((unsigned long long)__float_as_uint(best_d) << 32) \
          | (unsigned)best_k; \
    sec##r = sc; }

        PHASE1(0) PHASE1(1) PHASE1(2) PHASE1(3)
#undef PHASE1
#undef DIST1

        // ---------- phase 2: 4 interleaved butterfly reductions
        // best' = min_u64; sec' = min(secA, secB, max(bestA, bestB)).
        // u64 = (dist_bits<<32)|k -> exact min-dist + first-index tiebreak.
#pragma unroll
        for (int off = 32; off; off >>= 1) {
#define SHUF(r) { \
            const unsigned long long o  = __shfl_down(pk##r, off); \
            const float              os = __shfl_down(sec##r, off); \
            const float ax = __uint_as_float((unsigned)(pk##r >> 32)); \
            const float bx = __uint_as_float((unsigned)(o     >> 32)); \
            sec##r = fminf(fminf(sec##r, os), fmaxf(ax, bx)); \
            if (o < pk##r) pk##r = o; }
            SHUF(0) SHUF(1) SHUF(2) SHUF(3)
#undef SHUF
        }

        // ---------- phase 3: scalar broadcast, rare fp64 re-check, one_hot
        int bk0, bk1, bk2, bk3;

#define D641(i) { \
    double nd = dnrm4(d##i##_0, 0.0); nd = dnrm4(d##i##_1, nd); \
    nd = dnrm4(d##i##_2, nd); nd = dnrm4(d##i##_3, nd); \
    double dt = ddot4(d##i##_0, m0, 0.0); dt = ddot4(d##i##_1, m1, dt); \
    dt = ddot4(d##i##_2, m2, dt); dt = ddot4(d##i##_3, m3, dt); \
    const double dist = nmuD + nd - 2.0 * dt; \
    if (dist < bdd) { bdd = dist; bkk = lane + 64 * i; } }

#define PHASE3(r, BK) { \
    const int klo = __builtin_amdgcn_readfirstlane((int)(unsigned)pk##r); \
    const int dhi = __builtin_amdgcn_readfirstlane((int)(pk##r >> 32)); \
    const int shi = __builtin_amdgcn_readfirstlane(__float_as_int(sec##r)); \
    int bkr = klo; \
    if (__int_as_float(shi) - __int_as_float(dhi) < 1e-3f) { \
        /* wave-uniform, rare: exact fp64 re-evaluation */ \
        const int bl = wave + 16 * j + 4 * r; \
        const float4* mp = reinterpret_cast<const float4*>(&mu_s[bl][0]); \
        const float4 m0 = mp[0], m1 = mp[1], m2 = mp[2], m3 = mp[3]; \
        double nmuD = dnrm4(m0, 0.0); nmuD = dnrm4(m1, nmuD); \
        nmuD = dnrm4(m2, nmuD); nmuD = dnrm4(m3, nmuD); \
        double bdd = DBL_MAX; \
        int    bkk = K; \
        FOR8(D641) \
        _Pragma("unroll") \
        for (int off = 32; off; off >>= 1) { \
            const double od = __shfl_down(bdd, off); \
            const int    ok = __shfl_down(bkk, off); \
            if (od < bdd || (od == bdd && ok < bkk)) { bdd = od; bkk = ok; } \
        } \
        bkr = __builtin_amdgcn_readfirstlane(bkk); \
    } \
    BK = bkr; \
    { \
        const int bl = wave + 16 * j + 4 * r; \
        float* ohp = oh + ((size_t)(b0 + bl) * C + c) * K; \
        _Pragma("unroll") \
        for (int h = 0; h < 2; ++h) { \
            const int kb = h * 256 + lane * 4; \
            float4 v; \
            v.x = (kb + 0 == bkr) ? 1.0f : 0.0f; \
            v.y = (kb + 1 == bkr) ? 1.0f : 0.0f; \
            v.z = (kb + 2 == bkr) ? 1.0f : 0.0f; \
            v.w = (kb + 3 == bkr) ? 1.0f : 0.0f; \
            *reinterpret_cast<float4*>(ohp + kb) = v; \
        } \
    } }

        PHASE3(0, bk0) PHASE3(1, bk1) PHASE3(2, bk2) PHASE3(3, bk3)
#undef PHASE3
#undef D641

        // ---------- phase 4: z / zq for all 4 rows with one full wave
        {
            const int r = lane >> 4;        // sub-row 0..3
            const int e = lane & 15;        // embed dim
            int bkr = bk0;
            bkr = (r == 1) ? bk1 : bkr;
            bkr = (r == 2) ? bk2 : bkr;
            bkr = (r == 3) ? bk3 : bkr;
            const int bl = wave + 16 * j + 4 * r;
            const float dq = dbase[bkr * E + e];   // L2-hot
            const float mm = mu_s[bl][e];
            const size_t o = (size_t)(b0 + bl) * MUS + (size_t)c * E + e;
            zq[o] = dq;
            z[o]  = mm + (dq - mm);                // fp32 op-for-op like ref
        }
    }
#undef FOR8
}

extern "C" void kernel_launch(void* const* d_in, const int* in_sizes, int n_in,
                              void* d_out, int out_size, void* d_ws, size_t ws_size,
                              hipStream_t stream)
{
    const float* mu   = (const float*)d_in[0];
    const float* dict = (const float*)d_in[1];

    float* z  = (float*)d_out;                 // (B, C*E)
    float* zq = z  + (size_t)B * C * E;        // (B, C*E)
    float* oh = zq + (size_t)B * C * E;        // (B, C, K)

    dim3 grid(C, B / ROWS);
    vq_kernel<<<grid, 256, 0, stream>>>(mu, dict, z, zq, oh);
}